// Round 14
// baseline (427.460 us; speedup 1.0000x reference)
//
#include <hip/hip_runtime.h>
#include <hip/hip_bf16.h>
#include <cstdint>
#include <cstddef>

#define NNODES 20000
#define MNB    16
#define NFEAT  500
#define OUTC   656

typedef short short8 __attribute__((ext_vector_type(8)));
typedef float floatx4 __attribute__((ext_vector_type(4)));
typedef float v2f __attribute__((ext_vector_type(2)));

__device__ __forceinline__ float bf2f(unsigned int h) {
    union { unsigned int u; float f; } v; v.u = h << 16; return v.f;
}
__device__ __forceinline__ unsigned short f2bf(float f) {
    union { float f; unsigned int u; } v; v.f = f;
    unsigned int u = v.u;
    u += 0x7FFFu + ((u >> 16) & 1u);   // RNE
    return (unsigned short)(u >> 16);
}

// packed fp32 math (2x rate on CDNA): explicit VOP3P via asm.
__device__ __forceinline__ v2f pk_mul(v2f a, v2f b) {
    v2f d;
    asm("v_pk_mul_f32 %0, %1, %2 op_sel:[0,0] op_sel_hi:[1,1]"
        : "=v"(d) : "v"(a), "v"(b));
    return d;
}
__device__ __forceinline__ v2f pk_fma(v2f a, v2f b, v2f c) {
    v2f d;
    asm("v_pk_fma_f32 %0, %1, %2, %3 op_sel:[0,0,0] op_sel_hi:[1,1,1]"
        : "=v"(d) : "v"(a), "v"(b), "v"(c));
    return d;
}
__device__ __forceinline__ v2f pk_add(v2f a, v2f b) {
    v2f d;
    asm("v_pk_add_f32 %0, %1, %2 op_sel:[0,0] op_sel_hi:[1,1]"
        : "=v"(d) : "v"(a), "v"(b));
    return d;
}

// Opaque register pin: output of asm cannot be rematerialized from memory.
#define PIN(x) asm volatile("" : "+v"(x))

// DPP helpers. 0xB1 quad xor1, 0x4E quad xor2, 0x141 half-mirror (^7),
// 0x140 mirror (^15), 0x128 row_ror:8 (rot8 on 16 == xor8).
template<int CTRL>
__device__ __forceinline__ float dpp_add(float v) {
    const int o = __builtin_amdgcn_update_dpp(0, __float_as_int(v), CTRL, 0xF, 0xF, true);
    return v + __int_as_float(o);
}
__device__ __forceinline__ float sum16(float v) {
    v = dpp_add<0xB1>(v);
    v = dpp_add<0x4E>(v);
    v = dpp_add<0x141>(v);
    v = dpp_add<0x140>(v);
    return v;
}

// ---------------- dtype probe
__global__ __launch_bounds__(64) void detect_kernel(const unsigned short* __restrict__ fx,
                                                    int* __restrict__ flag) {
    const int tid = threadIdx.x;
    const unsigned short s = fx[2 * tid];
    const int e = (s >> 7) & 0xFF;
    const bool ok = (e >= 100 && e <= 140);
    const unsigned long long m = __ballot(ok);
    if (tid == 0) *flag = (__popcll(m) >= 32) ? 1 : 0;
}

// ---------------- convert all weights/biases to one fp32 blob in ws
struct WPtrs { const void* p[12]; };

__global__ __launch_bounds__(256) void convert_weights(WPtrs ptrs, const int* __restrict__ flag,
                                                       float* __restrict__ outb) {
    constexpr int SN[12] = {64000,128,14336,112,10752,96,7680,80,5120,64,3072,48};
    constexpr int SO[12] = {0,64000,64128,78464,78576,89328,89424,97104,97184,102304,102368,105440};
    constexpr int TOT = 105488;
    const int i = blockIdx.x * 256 + threadIdx.x;
    if (i >= TOT) return;
    const bool isbf = (*flag != 0);
    int seg = 0, local = i;
#pragma unroll
    for (int s = 0; s < 12; ++s) {
        if (i >= SO[s] && i < SO[s] + SN[s]) { seg = s; local = i - SO[s]; }
    }
    const void* src = ptrs.p[seg];
    float v;
    if (isbf) v = bf2f(((const unsigned short*)src)[local]);
    else      v = ((const float*)src)[local];
    outb[i] = v;
}

// ---------------- precompute bf16 hi/lo split of the 5 linear weight
// matrices, KP-padded with zeros: wh/wl[row][KP] per layer.
__global__ __launch_bounds__(256) void convert_wsplit(const float* __restrict__ wblob,
                                                      unsigned short* __restrict__ wh,
                                                      unsigned short* __restrict__ wl) {
    constexpr int NF[5]   = {128, 112, 96, 80, 64};    // FIN
    constexpr int KP[5]   = {128, 128, 96, 96, 64};    // padded K
    constexpr int WOFF[5] = {64128, 78576, 89424, 97184, 102368};
    constexpr int TOFF[5] = {0, 14336, 26624, 34304, 40448};
    constexpr int TOT = 43520;
    const int i = blockIdx.x * 256 + threadIdx.x;
    if (i >= TOT) return;
    int s = 0;
#pragma unroll
    for (int t = 1; t < 5; ++t) if (i >= TOFF[t]) s = t;
    const int local = i - TOFF[s];
    const int row = local / KP[s];
    const int k   = local % KP[s];
    unsigned short h = 0, lo = 0;
    if (k < NF[s]) {
        const float v = wblob[WOFF[s] + row * NF[s] + k];
        h  = f2bf(v);
        lo = f2bf(v - bf2f(h));
    }
    wh[i] = h;
    wl[i] = lo;
}

// ---------------- pad pca_w (fp32 blob) -> bf16 [128][512] (K-padded with zeros)
__global__ __launch_bounds__(256) void convert_wpad(const float* __restrict__ wblob,
                                                    unsigned short* __restrict__ wpad) {
    const int i = blockIdx.x * 256 + threadIdx.x;   // 128*512 = 65536
    const int n = i >> 9, k = i & 511;
    const float v = (k < NFEAT) ? wblob[n * NFEAT + k] : 0.f;
    wpad[i] = f2bf(v);
}

// ---------------- PCA via MFMA (fp32 OR bf16 feature; inline bf16 conversion)
__global__ __launch_bounds__(256) void pca_mfma(
    const void* __restrict__ feat_raw,
    const unsigned short* __restrict__ wpad,   // [128][512] bf16
    const float* __restrict__ bias,
    const int* __restrict__ flag,
    float* __restrict__ xn,
    void* __restrict__ out_raw)
{
    __shared__ short sA[32 * 56];   // stride 56 shorts (112 B): 2-way banks = free
    __shared__ short sB[128 * 56];
    const int tid = threadIdx.x;
    const int l = tid & 63, wv = tid >> 6;
    const int m = l & 15, q = l >> 4;
    const int rt = wv >> 1, ch = wv & 1;       // row-tile, col-half
    const int r0 = blockIdx.x * 32;
    const bool isbf = (*flag != 0);

    const int arow = tid >> 3, aseg = tid & 7;

    floatx4 acc[4];
#pragma unroll
    for (int t = 0; t < 4; ++t) acc[t] = 0;

    for (int c = 0; c < 16; ++c) {
        const int k0 = c * 32;
        __syncthreads();
        {
            const int k = k0 + aseg * 4;
            uint2 v = make_uint2(0u, 0u);
            if (k < NFEAT) {
                if (isbf) {
                    v = *(const uint2*)((const unsigned short*)feat_raw +
                                        (size_t)(r0 + arow) * NFEAT + k);
                } else {
                    const float4 f = *(const float4*)((const float*)feat_raw +
                                                      (size_t)(r0 + arow) * NFEAT + k);
                    v.x = ((unsigned int)f2bf(f.y) << 16) | f2bf(f.x);
                    v.y = ((unsigned int)f2bf(f.w) << 16) | f2bf(f.z);
                }
            }
            *(uint2*)&sA[arow * 56 + aseg * 4] = v;
        }
#pragma unroll
        for (int it = 0; it < 4; ++it) {
            const int idx = tid + 256 * it;
            const int row = idx >> 3, seg = idx & 7;
            const uint2 v = *(const uint2*)(wpad + (size_t)row * 512 + k0 + seg * 4);
            *(uint2*)&sB[row * 56 + seg * 4] = v;
        }
        __syncthreads();
        const short8 af = *(const short8*)&sA[(rt * 16 + m) * 56 + q * 8];
#pragma unroll
        for (int t = 0; t < 4; ++t) {
            const short8 bf = *(const short8*)&sB[((ch * 4 + t) * 16 + m) * 56 + q * 8];
            acc[t] = __builtin_amdgcn_mfma_f32_16x16x32_bf16(af, bf, acc[t], 0, 0, 0);
        }
    }

#pragma unroll
    for (int t = 0; t < 4; ++t) {
        const int col = (ch * 4 + t) * 16 + m;
        const float bb = bias[col];
#pragma unroll
        for (int r = 0; r < 4; ++r) {
            const int grow = r0 + rt * 16 + q * 4 + r;
            const float y = fmaxf(acc[t][r] + bb, 0.f);
            if (isbf) ((unsigned short*)out_raw)[(size_t)grow * OUTC + col] = f2bf(y);
            else      ((float*)out_raw)[(size_t)grow * OUTC + col] = y;
            const float ss = sum16(y * y);
            const float invn = 1.0f / fmaxf(sqrtf(ss), 1e-12f);
            xn[(size_t)grow * 128 + col] = y * invn;
        }
    }
}

// ---------------- linear via MFMA v3 (ROWS=16, precomputed hi/lo blobs;
// unchanged from round 13).
template<int FIN, int FOUT, int KP, int ROWS>
__global__ __launch_bounds__(256) void linear_mfma2(
    const float* __restrict__ xin,
    const unsigned short* __restrict__ wh,   // [FOUT][KP] bf16 hi
    const unsigned short* __restrict__ wl,   // [FOUT][KP] bf16 lo
    const float* __restrict__ bias,
    float* __restrict__ xn)
{
    constexpr int NCH  = KP / 32;
    constexpr int RT   = ROWS / 16;
    constexpr int NTIL = RT * (FOUT / 16);
    constexpr int MT   = (NTIL + 3) / 4;
    __shared__ short sAh[ROWS * 56], sAl[ROWS * 56];
    __shared__ short sBh[FOUT * 56], sBl[FOUT * 56];
    const int tid = threadIdx.x;
    const int l = tid & 63, wv = tid >> 6;
    const int m = l & 15, q = l >> 4;
    const int n0 = blockIdx.x * ROWS;

    floatx4 acc[MT];
#pragma unroll
    for (int i = 0; i < MT; ++i) acc[i] = 0;

    for (int c = 0; c < NCH; ++c) {
        const int k0 = c * 32;
        __syncthreads();
        for (int idx = tid; idx < ROWS * 8; idx += 256) {
            const int row = idx >> 3, seg = idx & 7;
            const int k = k0 + seg * 4;
            uint2 vh = make_uint2(0u, 0u), vl = make_uint2(0u, 0u);
            if (k < FIN) {
                const float4 f = *(const float4*)(xin + (size_t)(n0 + row) * FIN + k);
                const unsigned short h0 = f2bf(f.x), h1 = f2bf(f.y);
                const unsigned short h2 = f2bf(f.z), h3 = f2bf(f.w);
                const unsigned short e0 = f2bf(f.x - bf2f(h0)), e1 = f2bf(f.y - bf2f(h1));
                const unsigned short e2 = f2bf(f.z - bf2f(h2)), e3 = f2bf(f.w - bf2f(h3));
                vh = make_uint2(((unsigned)h1 << 16) | h0, ((unsigned)h3 << 16) | h2);
                vl = make_uint2(((unsigned)e1 << 16) | e0, ((unsigned)e3 << 16) | e2);
            }
            *(uint2*)&sAh[row * 56 + seg * 4] = vh;
            *(uint2*)&sAl[row * 56 + seg * 4] = vl;
        }
        for (int idx = tid; idx < FOUT * 4; idx += 256) {
            const int row = idx >> 2, qq = idx & 3;
            const short8 vh = *(const short8*)(wh + (size_t)row * KP + k0 + qq * 8);
            const short8 vl = *(const short8*)(wl + (size_t)row * KP + k0 + qq * 8);
            *(short8*)&sBh[row * 56 + qq * 8] = vh;
            *(short8*)&sBl[row * 56 + qq * 8] = vl;
        }
        __syncthreads();
#pragma unroll
        for (int ti = 0; ti < MT; ++ti) {
            const int t = wv + ti * 4;
            if (t < NTIL) {
                const int rt = t % RT, ct = t / RT;
                const int ao = (rt * 16 + m) * 56 + q * 8;
                const int bo = (ct * 16 + m) * 56 + q * 8;
                const short8 ah = *(const short8*)&sAh[ao];
                const short8 al = *(const short8*)&sAl[ao];
                const short8 bh = *(const short8*)&sBh[bo];
                const short8 bl = *(const short8*)&sBl[bo];
                floatx4 a = acc[ti];
                a = __builtin_amdgcn_mfma_f32_16x16x32_bf16(ah, bh, a, 0, 0, 0);
                a = __builtin_amdgcn_mfma_f32_16x16x32_bf16(ah, bl, a, 0, 0, 0);
                a = __builtin_amdgcn_mfma_f32_16x16x32_bf16(al, bh, a, 0, 0, 0);
                acc[ti] = a;
            }
        }
    }
#pragma unroll
    for (int ti = 0; ti < MT; ++ti) {
        const int t = wv + ti * 4;
        if (t < NTIL) {
            const int rt = t % RT, ct = t / RT;
            const int col = ct * 16 + m;
            const float bb = bias[col];
#pragma unroll
            for (int r = 0; r < 4; ++r) {
                const int grow = n0 + rt * 16 + q * 4 + r;
                const float y = acc[ti][r] + bb;
                const float ss = sum16(y * y);
                const float invn = __builtin_amdgcn_rsqf(fmaxf(ss, 1e-24f));
                xn[(size_t)grow * FOUT + col] = y * invn;
            }
        }
    }
}

// ---------------- routing v12: v11 with x EVICTED from registers. x is
// identical across the 8 m-lanes of a node and its use (post-butterfly add)
// is off the softmax critical path -- so re-read it from global (L2/L3-hot,
// loop-invariant address) each iteration instead of pinning 16 floats.
// State drops 64->48 pinned floats; target 5-6 waves/SIMD (was ~4).
template<int K, int NPW>
__global__ __launch_bounds__(256, 1) void routing_v12(
    const float* __restrict__ xn,
    const int* __restrict__ nb,
    float* __restrict__ xout,
    void* __restrict__ out_raw,
    const int* __restrict__ flag,
    const int coloff)
{
    constexpr int KD16 = K * 16;
    const int tid = threadIdx.x;
    const int l = tid & 63, wv = tid >> 6;
    const int m = l & 7;
    const int k = (l >> 3) & (NPW == 2 ? 3 : 7);
    const int nsub = (NPW == 2) ? (l >> 5) : 0;
    const int node = blockIdx.x * (4 * NPW) + wv * NPW + nsub;
    const bool kv = (k < K);
    const bool isbf = (*flag != 0);
    const int nid0 = nb[(size_t)node * 16 + m];
    const int nid1 = nb[(size_t)node * 16 + m + 8];
    const float* xp = xn + (size_t)node * KD16 + k * 16;

    v2f z0[8], z1[8], u[8];
    {
        const float* z0p = xn + (size_t)nid0 * KD16 + k * 16;
        const float* z1p = xn + (size_t)nid1 * KD16 + k * 16;
#pragma unroll
        for (int q = 0; q < 4; ++q) {
            float4 a = make_float4(0.f, 0.f, 0.f, 0.f);
            float4 b = a, c = a;
            if (kv) {
                a = *(const float4*)(z0p + q * 4);
                b = *(const float4*)(z1p + q * 4);
                c = *(const float4*)(xp  + q * 4);
            }
            z0[2 * q] = (v2f){a.x, a.y}; z0[2 * q + 1] = (v2f){a.z, a.w};
            z1[2 * q] = (v2f){b.x, b.y}; z1[2 * q + 1] = (v2f){b.z, b.w};
            u[2 * q]  = (v2f){c.x, c.y}; u[2 * q + 1]  = (v2f){c.z, c.w};
        }
    }
#pragma unroll
    for (int h = 0; h < 8; ++h) { PIN(z0[h]); PIN(z1[h]); }
    float invn = 1.0f;

    for (int t = 0; t < 5; ++t) {
        v2f d0 = pk_mul(z0[0], u[0]);
        v2f d1 = pk_mul(z1[0], u[0]);
#pragma unroll
        for (int h = 1; h < 8; ++h) {
            d0 = pk_fma(z0[h], u[h], d0);
            d1 = pk_fma(z1[h], u[h], d1);
        }
        const float p0 = kv ? (d0[0] + d0[1]) * invn : -1e4f;
        const float p1 = kv ? (d1[0] + d1[1]) * invn : -1e4f;
        float e0 = __expf(p0), e1 = __expf(p1);
        float s0 = dpp_add<0x128>(e0);
        float s1 = dpp_add<0x128>(e1);
        s0 += __shfl_xor(s0, 16);
        s1 += __shfl_xor(s1, 16);
        if (NPW == 1) {
            s0 += __shfl_xor(s0, 32);
            s1 += __shfl_xor(s1, 32);
        }
        e0 *= __builtin_amdgcn_rcpf(s0);
        e1 *= __builtin_amdgcn_rcpf(s1);
        const v2f ev0 = {e0, e0}, ev1 = {e1, e1};
#pragma unroll
        for (int h = 0; h < 8; ++h)
            u[h] = pk_fma(ev1, z1[h], pk_mul(ev0, z0[h]));
#pragma unroll
        for (int h = 0; h < 8; ++h) { u[h][0] = dpp_add<0xB1>(u[h][0]);  u[h][1] = dpp_add<0xB1>(u[h][1]); }
#pragma unroll
        for (int h = 0; h < 8; ++h) { u[h][0] = dpp_add<0x4E>(u[h][0]);  u[h][1] = dpp_add<0x4E>(u[h][1]); }
#pragma unroll
        for (int h = 0; h < 8; ++h) { u[h][0] = dpp_add<0x141>(u[h][0]); u[h][1] = dpp_add<0x141>(u[h][1]); }
        // + self term x: re-read from L2 (loop-invariant address, wave-dedup'd)
#pragma unroll
        for (int q = 0; q < 4; ++q) {
            float4 c = make_float4(0.f, 0.f, 0.f, 0.f);
            if (kv) c = *(const float4*)(xp + q * 4);
            u[2 * q]     = pk_add(u[2 * q],     (v2f){c.x, c.y});
            u[2 * q + 1] = pk_add(u[2 * q + 1], (v2f){c.z, c.w});
        }
        if (t < 4) {
            v2f n0 = pk_mul(u[0], u[0]);
            v2f n1 = pk_mul(u[1], u[1]);
#pragma unroll
            for (int h = 2; h < 8; h += 2) {
                n0 = pk_fma(u[h],     u[h],     n0);
                n1 = pk_fma(u[h + 1], u[h + 1], n1);
            }
            invn = __builtin_amdgcn_rsqf(fmaxf(n0[0] + n0[1] + n1[0] + n1[1], 1e-24f));
        }
    }

#pragma unroll
    for (int h = 0; h < 8; ++h) {
        u[h][0] = fmaxf(u[h][0], 0.f);
        u[h][1] = fmaxf(u[h][1], 0.f);
    }
    if (kv && m < 4) {
        v2f a = u[0], b = u[1];
        if (m == 1)      { a = u[2]; b = u[3]; }
        else if (m == 2) { a = u[4]; b = u[5]; }
        else if (m == 3) { a = u[6]; b = u[7]; }
        const float4 w4 = make_float4(a[0], a[1], b[0], b[1]);
        *(float4*)(xout + (size_t)node * KD16 + k * 16 + m * 4) = w4;
        const size_t ooff = (size_t)node * OUTC + coloff + k * 16 + m * 4;
        if (isbf) {
            uint2 pk;
            pk.x = ((unsigned int)f2bf(w4.y) << 16) | f2bf(w4.x);
            pk.y = ((unsigned int)f2bf(w4.w) << 16) | f2bf(w4.z);
            *(uint2*)((unsigned short*)out_raw + ooff) = pk;
        } else {
            *(float4*)((float*)out_raw + ooff) = w4;
        }
    }
}

extern "C" void kernel_launch(void* const* d_in, const int* in_sizes, int n_in,
                              void* d_out, int out_size, void* d_ws, size_t ws_size,
                              hipStream_t stream) {
    const int* nbid = (const int*)d_in[1];

    int*            flag  = (int*)d_ws;
    float*          wblob = (float*)((char*)d_ws + 16);
    unsigned short* wpad  = (unsigned short*)((char*)d_ws + (448 << 10));
    unsigned short* wh    = (unsigned short*)((char*)d_ws + (640 << 10));  // 87 KB
    unsigned short* wl    = (unsigned short*)((char*)d_ws + (768 << 10));  // 87 KB
    float*          xn    = (float*)((char*)d_ws + (1 << 20));
    float*          xc    = xn + (size_t)NNODES * 128;

    float* pb = wblob +  64000;
    float* b1 = wblob +  78464;
    float* b2 = wblob +  89328;
    float* b3 = wblob +  97104;
    float* b4 = wblob + 102304;
    float* b5 = wblob + 105440;
    float* pw = wblob;

    unsigned short* wh1 = wh +     0; unsigned short* wl1 = wl +     0;
    unsigned short* wh2 = wh + 14336; unsigned short* wl2 = wl + 14336;
    unsigned short* wh3 = wh + 26624; unsigned short* wl3 = wl + 26624;
    unsigned short* wh4 = wh + 34304; unsigned short* wl4 = wl + 34304;
    unsigned short* wh5 = wh + 40448; unsigned short* wl5 = wl + 40448;

    hipLaunchKernelGGL(detect_kernel, dim3(1), dim3(64), 0, stream,
                       (const unsigned short*)d_in[0], flag);

    WPtrs wp;
    for (int i = 0; i < 12; ++i) wp.p[i] = d_in[i + 2];
    hipLaunchKernelGGL(convert_weights, dim3(413), dim3(256), 0, stream, wp, flag, wblob);
    hipLaunchKernelGGL(convert_wpad, dim3(256), dim3(256), 0, stream, pw, wpad);
    hipLaunchKernelGGL(convert_wsplit, dim3(170), dim3(256), 0, stream, wblob, wh, wl);

    hipLaunchKernelGGL(pca_mfma, dim3(NNODES / 32), dim3(256), 0, stream,
                       d_in[0], wpad, pb, flag, xn, d_out);

    const int g1 = NNODES / 4;    // routing NPW=1: 4 nodes/block
    const int g2 = NNODES / 8;    // routing NPW=2: 8 nodes/block
    const int lg = NNODES / 16;   // linear: 16 nodes/block (grid 1250)

    hipLaunchKernelGGL((routing_v12<8, 1>), dim3(g1), dim3(256), 0, stream,
                       xn, nbid, xc, d_out, flag, 128);
    hipLaunchKernelGGL((linear_mfma2<128, 112, 128, 16>), dim3(lg), dim3(256), 0, stream,
                       xc, wh1, wl1, b1, xn);

    hipLaunchKernelGGL((routing_v12<7, 1>), dim3(g1), dim3(256), 0, stream,
                       xn, nbid, xc, d_out, flag, 256);
    hipLaunchKernelGGL((linear_mfma2<112, 96, 128, 16>), dim3(lg), dim3(256), 0, stream,
                       xc, wh2, wl2, b2, xn);

    hipLaunchKernelGGL((routing_v12<6, 1>), dim3(g1), dim3(256), 0, stream,
                       xn, nbid, xc, d_out, flag, 368);
    hipLaunchKernelGGL((linear_mfma2<96, 80, 96, 16>), dim3(lg), dim3(256), 0, stream,
                       xc, wh3, wl3, b3, xn);

    hipLaunchKernelGGL((routing_v12<5, 1>), dim3(g1), dim3(256), 0, stream,
                       xn, nbid, xc, d_out, flag, 464);
    hipLaunchKernelGGL((linear_mfma2<80, 64, 96, 16>), dim3(lg), dim3(256), 0, stream,
                       xc, wh4, wl4, b4, xn);

    hipLaunchKernelGGL((routing_v12<4, 2>), dim3(g2), dim3(256), 0, stream,
                       xn, nbid, xc, d_out, flag, 544);
    hipLaunchKernelGGL((linear_mfma2<64, 48, 64, 16>), dim3(lg), dim3(256), 0, stream,
                       xc, wh5, wl5, b5, xn);

    hipLaunchKernelGGL((routing_v12<3, 2>), dim3(g2), dim3(256), 0, stream,
                       xn, nbid, xc, d_out, flag, 608);
}

// Round 15
// 362.737 us; speedup vs baseline: 1.1784x; 1.1784x over previous
//
#include <hip/hip_runtime.h>
#include <hip/hip_bf16.h>
#include <cstdint>
#include <cstddef>

#define NNODES 20000
#define MNB    16
#define NFEAT  500
#define OUTC   656

typedef short short8 __attribute__((ext_vector_type(8)));
typedef float floatx4 __attribute__((ext_vector_type(4)));
typedef float v2f __attribute__((ext_vector_type(2)));

__device__ __forceinline__ float bf2f(unsigned int h) {
    union { unsigned int u; float f; } v; v.u = h << 16; return v.f;
}
__device__ __forceinline__ unsigned short f2bf(float f) {
    union { float f; unsigned int u; } v; v.f = f;
    unsigned int u = v.u;
    u += 0x7FFFu + ((u >> 16) & 1u);   // RNE
    return (unsigned short)(u >> 16);
}

// packed fp32 math (2x rate on CDNA): explicit VOP3P via asm.
__device__ __forceinline__ v2f pk_mul(v2f a, v2f b) {
    v2f d;
    asm("v_pk_mul_f32 %0, %1, %2 op_sel:[0,0] op_sel_hi:[1,1]"
        : "=v"(d) : "v"(a), "v"(b));
    return d;
}
__device__ __forceinline__ v2f pk_fma(v2f a, v2f b, v2f c) {
    v2f d;
    asm("v_pk_fma_f32 %0, %1, %2, %3 op_sel:[0,0,0] op_sel_hi:[1,1,1]"
        : "=v"(d) : "v"(a), "v"(b), "v"(c));
    return d;
}
__device__ __forceinline__ v2f pk_add(v2f a, v2f b) {
    v2f d;
    asm("v_pk_add_f32 %0, %1, %2 op_sel:[0,0] op_sel_hi:[1,1]"
        : "=v"(d) : "v"(a), "v"(b));
    return d;
}

// Opaque register pin: output of asm cannot be rematerialized from memory.
#define PIN(x) asm volatile("" : "+v"(x))

// DPP helpers. 0xB1 quad xor1, 0x4E quad xor2, 0x141 half-mirror (^7),
// 0x140 mirror (^15), 0x128 row_ror:8 (rot8 on 16 == xor8).
template<int CTRL>
__device__ __forceinline__ float dpp_add(float v) {
    const int o = __builtin_amdgcn_update_dpp(0, __float_as_int(v), CTRL, 0xF, 0xF, true);
    return v + __int_as_float(o);
}
__device__ __forceinline__ float sum16(float v) {
    v = dpp_add<0xB1>(v);
    v = dpp_add<0x4E>(v);
    v = dpp_add<0x141>(v);
    v = dpp_add<0x140>(v);
    return v;
}

// ---------------- dtype probe
__global__ __launch_bounds__(64) void detect_kernel(const unsigned short* __restrict__ fx,
                                                    int* __restrict__ flag) {
    const int tid = threadIdx.x;
    const unsigned short s = fx[2 * tid];
    const int e = (s >> 7) & 0xFF;
    const bool ok = (e >= 100 && e <= 140);
    const unsigned long long m = __ballot(ok);
    if (tid == 0) *flag = (__popcll(m) >= 32) ? 1 : 0;
}

// ---------------- convert all weights/biases to one fp32 blob in ws
struct WPtrs { const void* p[12]; };

__global__ __launch_bounds__(256) void convert_weights(WPtrs ptrs, const int* __restrict__ flag,
                                                       float* __restrict__ outb) {
    constexpr int SN[12] = {64000,128,14336,112,10752,96,7680,80,5120,64,3072,48};
    constexpr int SO[12] = {0,64000,64128,78464,78576,89328,89424,97104,97184,102304,102368,105440};
    constexpr int TOT = 105488;
    const int i = blockIdx.x * 256 + threadIdx.x;
    if (i >= TOT) return;
    const bool isbf = (*flag != 0);
    int seg = 0, local = i;
#pragma unroll
    for (int s = 0; s < 12; ++s) {
        if (i >= SO[s] && i < SO[s] + SN[s]) { seg = s; local = i - SO[s]; }
    }
    const void* src = ptrs.p[seg];
    float v;
    if (isbf) v = bf2f(((const unsigned short*)src)[local]);
    else      v = ((const float*)src)[local];
    outb[i] = v;
}

// ---------------- precompute bf16 hi/lo split of the 5 linear weight
// matrices, KP-padded with zeros: wh/wl[row][KP] per layer.
__global__ __launch_bounds__(256) void convert_wsplit(const float* __restrict__ wblob,
                                                      unsigned short* __restrict__ wh,
                                                      unsigned short* __restrict__ wl) {
    constexpr int NF[5]   = {128, 112, 96, 80, 64};    // FIN
    constexpr int KP[5]   = {128, 128, 96, 96, 64};    // padded K
    constexpr int WOFF[5] = {64128, 78576, 89424, 97184, 102368};
    constexpr int TOFF[5] = {0, 14336, 26624, 34304, 40448};
    constexpr int TOT = 43520;
    const int i = blockIdx.x * 256 + threadIdx.x;
    if (i >= TOT) return;
    int s = 0;
#pragma unroll
    for (int t = 1; t < 5; ++t) if (i >= TOFF[t]) s = t;
    const int local = i - TOFF[s];
    const int row = local / KP[s];
    const int k   = local % KP[s];
    unsigned short h = 0, lo = 0;
    if (k < NF[s]) {
        const float v = wblob[WOFF[s] + row * NF[s] + k];
        h  = f2bf(v);
        lo = f2bf(v - bf2f(h));
    }
    wh[i] = h;
    wl[i] = lo;
}

// ---------------- pad pca_w (fp32 blob) -> bf16 [128][512] (K-padded with zeros)
__global__ __launch_bounds__(256) void convert_wpad(const float* __restrict__ wblob,
                                                    unsigned short* __restrict__ wpad) {
    const int i = blockIdx.x * 256 + threadIdx.x;   // 128*512 = 65536
    const int n = i >> 9, k = i & 511;
    const float v = (k < NFEAT) ? wblob[n * NFEAT + k] : 0.f;
    wpad[i] = f2bf(v);
}

// ---------------- PCA via MFMA (fp32 OR bf16 feature; inline bf16 conversion)
__global__ __launch_bounds__(256) void pca_mfma(
    const void* __restrict__ feat_raw,
    const unsigned short* __restrict__ wpad,   // [128][512] bf16
    const float* __restrict__ bias,
    const int* __restrict__ flag,
    float* __restrict__ xn,
    void* __restrict__ out_raw)
{
    __shared__ short sA[32 * 56];   // stride 56 shorts (112 B): 2-way banks = free
    __shared__ short sB[128 * 56];
    const int tid = threadIdx.x;
    const int l = tid & 63, wv = tid >> 6;
    const int m = l & 15, q = l >> 4;
    const int rt = wv >> 1, ch = wv & 1;       // row-tile, col-half
    const int r0 = blockIdx.x * 32;
    const bool isbf = (*flag != 0);

    const int arow = tid >> 3, aseg = tid & 7;

    floatx4 acc[4];
#pragma unroll
    for (int t = 0; t < 4; ++t) acc[t] = 0;

    for (int c = 0; c < 16; ++c) {
        const int k0 = c * 32;
        __syncthreads();
        {
            const int k = k0 + aseg * 4;
            uint2 v = make_uint2(0u, 0u);
            if (k < NFEAT) {
                if (isbf) {
                    v = *(const uint2*)((const unsigned short*)feat_raw +
                                        (size_t)(r0 + arow) * NFEAT + k);
                } else {
                    const float4 f = *(const float4*)((const float*)feat_raw +
                                                      (size_t)(r0 + arow) * NFEAT + k);
                    v.x = ((unsigned int)f2bf(f.y) << 16) | f2bf(f.x);
                    v.y = ((unsigned int)f2bf(f.w) << 16) | f2bf(f.z);
                }
            }
            *(uint2*)&sA[arow * 56 + aseg * 4] = v;
        }
#pragma unroll
        for (int it = 0; it < 4; ++it) {
            const int idx = tid + 256 * it;
            const int row = idx >> 3, seg = idx & 7;
            const uint2 v = *(const uint2*)(wpad + (size_t)row * 512 + k0 + seg * 4);
            *(uint2*)&sB[row * 56 + seg * 4] = v;
        }
        __syncthreads();
        const short8 af = *(const short8*)&sA[(rt * 16 + m) * 56 + q * 8];
#pragma unroll
        for (int t = 0; t < 4; ++t) {
            const short8 bf = *(const short8*)&sB[((ch * 4 + t) * 16 + m) * 56 + q * 8];
            acc[t] = __builtin_amdgcn_mfma_f32_16x16x32_bf16(af, bf, acc[t], 0, 0, 0);
        }
    }

#pragma unroll
    for (int t = 0; t < 4; ++t) {
        const int col = (ch * 4 + t) * 16 + m;
        const float bb = bias[col];
#pragma unroll
        for (int r = 0; r < 4; ++r) {
            const int grow = r0 + rt * 16 + q * 4 + r;
            const float y = fmaxf(acc[t][r] + bb, 0.f);
            if (isbf) ((unsigned short*)out_raw)[(size_t)grow * OUTC + col] = f2bf(y);
            else      ((float*)out_raw)[(size_t)grow * OUTC + col] = y;
            const float ss = sum16(y * y);
            const float invn = 1.0f / fmaxf(sqrtf(ss), 1e-12f);
            xn[(size_t)grow * 128 + col] = y * invn;
        }
    }
}

// ---------------- linear via MFMA (precomputed hi/lo blobs; ROWS=32 = the
// proven r12 champion configuration).
template<int FIN, int FOUT, int KP, int ROWS>
__global__ __launch_bounds__(256) void linear_mfma2(
    const float* __restrict__ xin,
    const unsigned short* __restrict__ wh,   // [FOUT][KP] bf16 hi
    const unsigned short* __restrict__ wl,   // [FOUT][KP] bf16 lo
    const float* __restrict__ bias,
    float* __restrict__ xn)
{
    constexpr int NCH  = KP / 32;
    constexpr int RT   = ROWS / 16;
    constexpr int NTIL = RT * (FOUT / 16);
    constexpr int MT   = (NTIL + 3) / 4;
    __shared__ short sAh[ROWS * 56], sAl[ROWS * 56];
    __shared__ short sBh[FOUT * 56], sBl[FOUT * 56];
    const int tid = threadIdx.x;
    const int l = tid & 63, wv = tid >> 6;
    const int m = l & 15, q = l >> 4;
    const int n0 = blockIdx.x * ROWS;

    floatx4 acc[MT];
#pragma unroll
    for (int i = 0; i < MT; ++i) acc[i] = 0;

    for (int c = 0; c < NCH; ++c) {
        const int k0 = c * 32;
        __syncthreads();
        for (int idx = tid; idx < ROWS * 8; idx += 256) {
            const int row = idx >> 3, seg = idx & 7;
            const int k = k0 + seg * 4;
            uint2 vh = make_uint2(0u, 0u), vl = make_uint2(0u, 0u);
            if (k < FIN) {
                const float4 f = *(const float4*)(xin + (size_t)(n0 + row) * FIN + k);
                const unsigned short h0 = f2bf(f.x), h1 = f2bf(f.y);
                const unsigned short h2 = f2bf(f.z), h3 = f2bf(f.w);
                const unsigned short e0 = f2bf(f.x - bf2f(h0)), e1 = f2bf(f.y - bf2f(h1));
                const unsigned short e2 = f2bf(f.z - bf2f(h2)), e3 = f2bf(f.w - bf2f(h3));
                vh = make_uint2(((unsigned)h1 << 16) | h0, ((unsigned)h3 << 16) | h2);
                vl = make_uint2(((unsigned)e1 << 16) | e0, ((unsigned)e3 << 16) | e2);
            }
            *(uint2*)&sAh[row * 56 + seg * 4] = vh;
            *(uint2*)&sAl[row * 56 + seg * 4] = vl;
        }
        for (int idx = tid; idx < FOUT * 4; idx += 256) {
            const int row = idx >> 2, qq = idx & 3;
            const short8 vh = *(const short8*)(wh + (size_t)row * KP + k0 + qq * 8);
            const short8 vl = *(const short8*)(wl + (size_t)row * KP + k0 + qq * 8);
            *(short8*)&sBh[row * 56 + qq * 8] = vh;
            *(short8*)&sBl[row * 56 + qq * 8] = vl;
        }
        __syncthreads();
#pragma unroll
        for (int ti = 0; ti < MT; ++ti) {
            const int t = wv + ti * 4;
            if (t < NTIL) {
                const int rt = t % RT, ct = t / RT;
                const int ao = (rt * 16 + m) * 56 + q * 8;
                const int bo = (ct * 16 + m) * 56 + q * 8;
                const short8 ah = *(const short8*)&sAh[ao];
                const short8 al = *(const short8*)&sAl[ao];
                const short8 bh = *(const short8*)&sBh[bo];
                const short8 bl = *(const short8*)&sBl[bo];
                floatx4 a = acc[ti];
                a = __builtin_amdgcn_mfma_f32_16x16x32_bf16(ah, bh, a, 0, 0, 0);
                a = __builtin_amdgcn_mfma_f32_16x16x32_bf16(ah, bl, a, 0, 0, 0);
                a = __builtin_amdgcn_mfma_f32_16x16x32_bf16(al, bh, a, 0, 0, 0);
                acc[ti] = a;
            }
        }
    }
#pragma unroll
    for (int ti = 0; ti < MT; ++ti) {
        const int t = wv + ti * 4;
        if (t < NTIL) {
            const int rt = t % RT, ct = t / RT;
            const int col = ct * 16 + m;
            const float bb = bias[col];
#pragma unroll
            for (int r = 0; r < 4; ++r) {
                const int grow = n0 + rt * 16 + q * 4 + r;
                const float y = acc[ti][r] + bb;
                const float ss = sum16(y * y);
                const float invn = __builtin_amdgcn_rsqf(fmaxf(ss, 1e-24f));
                xn[(size_t)grow * FOUT + col] = y * invn;
            }
        }
    }
}

// ---------------- routing v11 (register-resident; the proven r8/r12
// configuration, byte-identical math). WROUT=false skips the dead xout
// store for the final layer (nothing consumes it).
template<int K, int NPW, bool WROUT>
__global__ __launch_bounds__(256, 1) void routing_v11(
    const float* __restrict__ xn,
    const int* __restrict__ nb,
    float* __restrict__ xout,
    void* __restrict__ out_raw,
    const int* __restrict__ flag,
    const int coloff)
{
    constexpr int KD16 = K * 16;
    const int tid = threadIdx.x;
    const int l = tid & 63, wv = tid >> 6;
    const int m = l & 7;
    const int k = (l >> 3) & (NPW == 2 ? 3 : 7);
    const int nsub = (NPW == 2) ? (l >> 5) : 0;
    const int node = blockIdx.x * (4 * NPW) + wv * NPW + nsub;
    const bool kv = (k < K);
    const bool isbf = (*flag != 0);
    const int nid0 = nb[(size_t)node * 16 + m];
    const int nid1 = nb[(size_t)node * 16 + m + 8];

    v2f z0[8], z1[8], x[8], u[8];
    {
        const float* z0p = xn + (size_t)nid0 * KD16 + k * 16;
        const float* z1p = xn + (size_t)nid1 * KD16 + k * 16;
        const float* xp  = xn + (size_t)node * KD16 + k * 16;
#pragma unroll
        for (int q = 0; q < 4; ++q) {
            float4 a = make_float4(0.f, 0.f, 0.f, 0.f);
            float4 b = a, c = a;
            if (kv) {
                a = *(const float4*)(z0p + q * 4);
                b = *(const float4*)(z1p + q * 4);
                c = *(const float4*)(xp  + q * 4);
            }
            z0[2 * q] = (v2f){a.x, a.y}; z0[2 * q + 1] = (v2f){a.z, a.w};
            z1[2 * q] = (v2f){b.x, b.y}; z1[2 * q + 1] = (v2f){b.z, b.w};
            x[2 * q]  = (v2f){c.x, c.y}; x[2 * q + 1]  = (v2f){c.z, c.w};
            u[2 * q]  = (v2f){c.x, c.y}; u[2 * q + 1]  = (v2f){c.z, c.w};
        }
    }
#pragma unroll
    for (int h = 0; h < 8; ++h) { PIN(z0[h]); PIN(z1[h]); PIN(x[h]); }
    float invn = 1.0f;

    for (int t = 0; t < 5; ++t) {
        v2f d0 = pk_mul(z0[0], u[0]);
        v2f d1 = pk_mul(z1[0], u[0]);
#pragma unroll
        for (int h = 1; h < 8; ++h) {
            d0 = pk_fma(z0[h], u[h], d0);
            d1 = pk_fma(z1[h], u[h], d1);
        }
        const float p0 = kv ? (d0[0] + d0[1]) * invn : -1e4f;
        const float p1 = kv ? (d1[0] + d1[1]) * invn : -1e4f;
        float e0 = __expf(p0), e1 = __expf(p1);
        float s0 = dpp_add<0x128>(e0);
        float s1 = dpp_add<0x128>(e1);
        s0 += __shfl_xor(s0, 16);
        s1 += __shfl_xor(s1, 16);
        if (NPW == 1) {
            s0 += __shfl_xor(s0, 32);
            s1 += __shfl_xor(s1, 32);
        }
        e0 *= __builtin_amdgcn_rcpf(s0);
        e1 *= __builtin_amdgcn_rcpf(s1);
        const v2f ev0 = {e0, e0}, ev1 = {e1, e1};
#pragma unroll
        for (int h = 0; h < 8; ++h)
            u[h] = pk_fma(ev1, z1[h], pk_mul(ev0, z0[h]));
#pragma unroll
        for (int h = 0; h < 8; ++h) { u[h][0] = dpp_add<0xB1>(u[h][0]);  u[h][1] = dpp_add<0xB1>(u[h][1]); }
#pragma unroll
        for (int h = 0; h < 8; ++h) { u[h][0] = dpp_add<0x4E>(u[h][0]);  u[h][1] = dpp_add<0x4E>(u[h][1]); }
#pragma unroll
        for (int h = 0; h < 8; ++h) { u[h][0] = dpp_add<0x141>(u[h][0]); u[h][1] = dpp_add<0x141>(u[h][1]); }
#pragma unroll
        for (int h = 0; h < 8; ++h) u[h] = pk_add(u[h], x[h]);
        if (t < 4) {
            v2f n0 = pk_mul(u[0], u[0]);
            v2f n1 = pk_mul(u[1], u[1]);
#pragma unroll
            for (int h = 2; h < 8; h += 2) {
                n0 = pk_fma(u[h],     u[h],     n0);
                n1 = pk_fma(u[h + 1], u[h + 1], n1);
            }
            invn = __builtin_amdgcn_rsqf(fmaxf(n0[0] + n0[1] + n1[0] + n1[1], 1e-24f));
        }
    }

#pragma unroll
    for (int h = 0; h < 8; ++h) {
        u[h][0] = fmaxf(u[h][0], 0.f);
        u[h][1] = fmaxf(u[h][1], 0.f);
    }
    if (kv && m < 4) {
        v2f a = u[0], b = u[1];
        if (m == 1)      { a = u[2]; b = u[3]; }
        else if (m == 2) { a = u[4]; b = u[5]; }
        else if (m == 3) { a = u[6]; b = u[7]; }
        const float4 w4 = make_float4(a[0], a[1], b[0], b[1]);
        if (WROUT) {
            *(float4*)(xout + (size_t)node * KD16 + k * 16 + m * 4) = w4;
        }
        const size_t ooff = (size_t)node * OUTC + coloff + k * 16 + m * 4;
        if (isbf) {
            uint2 pk;
            pk.x = ((unsigned int)f2bf(w4.y) << 16) | f2bf(w4.x);
            pk.y = ((unsigned int)f2bf(w4.w) << 16) | f2bf(w4.z);
            *(uint2*)((unsigned short*)out_raw + ooff) = pk;
        } else {
            *(float4*)((float*)out_raw + ooff) = w4;
        }
    }
}

extern "C" void kernel_launch(void* const* d_in, const int* in_sizes, int n_in,
                              void* d_out, int out_size, void* d_ws, size_t ws_size,
                              hipStream_t stream) {
    const int* nbid = (const int*)d_in[1];

    int*            flag  = (int*)d_ws;
    float*          wblob = (float*)((char*)d_ws + 16);
    unsigned short* wpad  = (unsigned short*)((char*)d_ws + (448 << 10));
    unsigned short* wh    = (unsigned short*)((char*)d_ws + (640 << 10));  // 87 KB
    unsigned short* wl    = (unsigned short*)((char*)d_ws + (768 << 10));  // 87 KB
    float*          xn    = (float*)((char*)d_ws + (1 << 20));
    float*          xc    = xn + (size_t)NNODES * 128;

    float* pb = wblob +  64000;
    float* b1 = wblob +  78464;
    float* b2 = wblob +  89328;
    float* b3 = wblob +  97104;
    float* b4 = wblob + 102304;
    float* b5 = wblob + 105440;
    float* pw = wblob;

    unsigned short* wh1 = wh +     0; unsigned short* wl1 = wl +     0;
    unsigned short* wh2 = wh + 14336; unsigned short* wl2 = wl + 14336;
    unsigned short* wh3 = wh + 26624; unsigned short* wl3 = wl + 26624;
    unsigned short* wh4 = wh + 34304; unsigned short* wl4 = wl + 34304;
    unsigned short* wh5 = wh + 40448; unsigned short* wl5 = wl + 40448;

    hipLaunchKernelGGL(detect_kernel, dim3(1), dim3(64), 0, stream,
                       (const unsigned short*)d_in[0], flag);

    WPtrs wp;
    for (int i = 0; i < 12; ++i) wp.p[i] = d_in[i + 2];
    hipLaunchKernelGGL(convert_weights, dim3(413), dim3(256), 0, stream, wp, flag, wblob);
    hipLaunchKernelGGL(convert_wpad, dim3(256), dim3(256), 0, stream, pw, wpad);
    hipLaunchKernelGGL(convert_wsplit, dim3(170), dim3(256), 0, stream, wblob, wh, wl);

    hipLaunchKernelGGL(pca_mfma, dim3(NNODES / 32), dim3(256), 0, stream,
                       d_in[0], wpad, pb, flag, xn, d_out);

    const int g1 = NNODES / 4;    // routing NPW=1: 4 nodes/block
    const int g2 = NNODES / 8;    // routing NPW=2: 8 nodes/block
    const int lg = NNODES / 32;   // linear: 32 nodes/block (r12 champion)

    hipLaunchKernelGGL((routing_v11<8, 1, true>), dim3(g1), dim3(256), 0, stream,
                       xn, nbid, xc, d_out, flag, 128);
    hipLaunchKernelGGL((linear_mfma2<128, 112, 128, 32>), dim3(lg), dim3(256), 0, stream,
                       xc, wh1, wl1, b1, xn);

    hipLaunchKernelGGL((routing_v11<7, 1, true>), dim3(g1), dim3(256), 0, stream,
                       xn, nbid, xc, d_out, flag, 256);
    hipLaunchKernelGGL((linear_mfma2<112, 96, 128, 32>), dim3(lg), dim3(256), 0, stream,
                       xc, wh2, wl2, b2, xn);

    hipLaunchKernelGGL((routing_v11<6, 1, true>), dim3(g1), dim3(256), 0, stream,
                       xn, nbid, xc, d_out, flag, 368);
    hipLaunchKernelGGL((linear_mfma2<96, 80, 96, 32>), dim3(lg), dim3(256), 0, stream,
                       xc, wh3, wl3, b3, xn);

    hipLaunchKernelGGL((routing_v11<5, 1, true>), dim3(g1), dim3(256), 0, stream,
                       xn, nbid, xc, d_out, flag, 464);
    hipLaunchKernelGGL((linear_mfma2<80, 64, 96, 32>), dim3(lg), dim3(256), 0, stream,
                       xc, wh4, wl4, b4, xn);

    hipLaunchKernelGGL((routing_v11<4, 2, true>), dim3(g2), dim3(256), 0, stream,
                       xn, nbid, xc, d_out, flag, 544);
    hipLaunchKernelGGL((linear_mfma2<64, 48, 64, 32>), dim3(lg), dim3(256), 0, stream,
                       xc, wh5, wl5, b5, xn);

    hipLaunchKernelGGL((routing_v11<3, 2, false>), dim3(g2), dim3(256), 0, stream,
                       xn, nbid, xc, d_out, flag, 608);
}